// Round 1
// baseline (983.608 us; speedup 1.0000x reference)
//
#include <hip/hip_runtime.h>

// Problem constants
#define BN   64
#define LN   1024
#define DKN  64
#define PN   2047          // 2*L - 1
#define OUT_O_ELEMS ((size_t)BN * LN * DKN)   // 4,194,304
constexpr float kScale = 0.125f;              // 1/sqrt(64)

typedef short bf16x8 __attribute__((ext_vector_type(8)));
typedef float f32x4  __attribute__((ext_vector_type(4)));

__device__ __forceinline__ unsigned short f2b(float f) {
  unsigned u = __float_as_uint(f);
  u = (u + 0x7FFFu + ((u >> 16) & 1u)) >> 16;   // RNE
  return (unsigned short)u;
}
__device__ __forceinline__ float b2f(unsigned short h) {
  return __uint_as_float(((unsigned)h) << 16);
}

// ---------- mask dtype detection ----------
// flag bit1 -> float32 evidence (word == 0x3F800000)
// flag bit2 -> packed-byte evidence (word > 1 and != 0x3F800000)
__global__ void flag_init(unsigned* f) { *f = 0u; }

__global__ void flag_scan(const unsigned* __restrict__ mw, unsigned* f) {
  int idx = blockIdx.x * 256 + threadIdx.x;
  unsigned bits = 0;
#pragma unroll
  for (int i = 0; i < 4; ++i) {
    unsigned wv = mw[idx * 4 + i];
    if (wv == 0x3F800000u) bits |= 2u;
    else if (wv > 1u)      bits |= 4u;
  }
  if (bits) atomicOr(f, bits);
}

// ---------- main fused kernel ----------
// Block: b fixed, 16 query rows [l0, l0+16). 256 threads = 4 waves.
// Wave w computes S for m-subcolumns [m0+16w, m0+16w+16) and PV for d in [16w,16w+16).
__global__ __launch_bounds__(256)
void attn_kernel(const float* __restrict__ q, const float* __restrict__ k,
                 const float* __restrict__ v, const float* __restrict__ pos,
                 const void* __restrict__ mask, const unsigned* __restrict__ flagp,
                 float* __restrict__ out) {
  __shared__ short qA[16 * 72];     // q rows, bf16, stride 72 (pad: 2-way free)
  __shared__ short qrA[16 * 72];    // reversed q rows
  __shared__ short kvS[64 * 72];    // k tile, later re-used as v^T tile
  __shared__ short posS[80 * 72];   // pos tile (needs TL+TM-1=79 rows)
  __shared__ short E[16 * 1032];    // unnormalized exp(s), bf16, stride 1032
  __shared__ float rowSum[16];
  __shared__ float invSum[16];

  const int tid  = threadIdx.x;
  const int w    = tid >> 6;
  const int lane = tid & 63;
  const int col  = lane & 15;
  const int quad = lane >> 4;

  // XCD swizzle: all 64 row-tiles of one b land on the same XCD (L2 reuse of k/v/pos)
  int p   = blockIdx.x;
  int xcd = p & 7;
  int qq  = p >> 3;
  int rt  = qq & 63;
  int bh  = qq >> 6;
  const int b  = (bh << 3) | xcd;
  const int l0 = rt << 4;

  unsigned mflag = flagp ? flagp[0] : 0u;
  const int mkind = (mflag & 4u) ? 1 : ((mflag & 2u) ? 2 : 0);  // 0=int32 1=u8 2=f32

  if (tid < 16) rowSum[tid] = 0.0f;

  // stage qA / qrA (16 rows x 16 float4 each; 256 threads = 1 float4 each)
  {
    const float4* qg = (const float4*)q;
    int row = tid >> 4, c4 = tid & 15;
    float4 a  = qg[((size_t)b * LN + (l0 + row)) * 16 + c4];
    float4 r_ = qg[((size_t)b * LN + (LN - 1 - l0 - row)) * 16 + c4];
    short* d0 = &qA[row * 72 + c4 * 4];
    d0[0] = (short)f2b(a.x);  d0[1] = (short)f2b(a.y);
    d0[2] = (short)f2b(a.z);  d0[3] = (short)f2b(a.w);
    short* d1 = &qrA[row * 72 + c4 * 4];
    d1[0] = (short)f2b(r_.x); d1[1] = (short)f2b(r_.y);
    d1[2] = (short)f2b(r_.z); d1[3] = (short)f2b(r_.w);
  }
  __syncthreads();

  // hoisted A-fragments: A[m=lane&15][k=quad*8+j]
  const bf16x8 aq0 = *(const bf16x8*)&qA[col * 72 + quad * 8];
  const bf16x8 aq1 = *(const bf16x8*)&qA[col * 72 + quad * 8 + 32];
  const bf16x8 ar0 = *(const bf16x8*)&qrA[col * 72 + quad * 8];
  const bf16x8 ar1 = *(const bf16x8*)&qrA[col * 72 + quad * 8 + 32];

  f32x4 acc = {0.f, 0.f, 0.f, 0.f};   // PV accumulator: O[l=quad*4+r][d=16w+col]
  float sumr[4] = {0.f, 0.f, 0.f, 0.f};

  for (int t = 0; t < 16; ++t) {
    const int m0 = t << 6;
    __syncthreads();
    // ---- stage k tile (64x64) and pos tile (80x64) as bf16 ----
    {
      const float4* kg = (const float4*)(k + ((size_t)b * LN + m0) * DKN);
#pragma unroll
      for (int i = 0; i < 4; ++i) {
        int j = tid + (i << 8);
        int row = j >> 4, c4 = j & 15;
        float4 a = kg[j];
        short* d = &kvS[row * 72 + c4 * 4];
        d[0] = (short)f2b(a.x); d[1] = (short)f2b(a.y);
        d[2] = (short)f2b(a.z); d[3] = (short)f2b(a.w);
      }
      const int pbase = l0 + m0;
      const float4* pg = (const float4*)pos;
#pragma unroll
      for (int i = 0; i < 5; ++i) {
        int j = tid + (i << 8);
        int row = j >> 4, c4 = j & 15;
        int gr = pbase + row;
        if (gr > PN - 1) gr = PN - 1;      // clamp; clamped rows are never consumed
        float4 a = pg[((size_t)b * PN + gr) * 16 + c4];
        short* d = &posS[row * 72 + c4 * 4];
        d[0] = (short)f2b(a.x); d[1] = (short)f2b(a.y);
        d[2] = (short)f2b(a.z); d[3] = (short)f2b(a.w);
      }
    }
    __syncthreads();
    // ---- scores + exp + E store ----
    {
      const int mrow = (w << 4) + col;               // B-frag n = m-offset
      bf16x8 kb0 = *(const bf16x8*)&kvS[mrow * 72 + quad * 8];
      bf16x8 kb1 = *(const bf16x8*)&kvS[mrow * 72 + quad * 8 + 32];
      f32x4 qk = {0.f, 0.f, 0.f, 0.f};
      qk = __builtin_amdgcn_mfma_f32_16x16x32_bf16(aq0, kb0, qk, 0, 0, 0);
      qk = __builtin_amdgcn_mfma_f32_16x16x32_bf16(aq1, kb1, qk, 0, 0, 0);

      // Bias2[i][o] for o in [0,32): p = l0+m0+16w+o
      const int pr0 = (w << 4) + col;
      const int pr1 = pr0 + 16;
      bf16x8 pb00 = *(const bf16x8*)&posS[pr0 * 72 + quad * 8];
      bf16x8 pb01 = *(const bf16x8*)&posS[pr0 * 72 + quad * 8 + 32];
      bf16x8 pb10 = *(const bf16x8*)&posS[pr1 * 72 + quad * 8];
      bf16x8 pb11 = *(const bf16x8*)&posS[pr1 * 72 + quad * 8 + 32];
      f32x4 ba = {0.f, 0.f, 0.f, 0.f}, bb = {0.f, 0.f, 0.f, 0.f};
      ba = __builtin_amdgcn_mfma_f32_16x16x32_bf16(ar0, pb00, ba, 0, 0, 0);
      ba = __builtin_amdgcn_mfma_f32_16x16x32_bf16(ar1, pb01, ba, 0, 0, 0);
      bb = __builtin_amdgcn_mfma_f32_16x16x32_bf16(ar0, pb10, bb, 0, 0, 0);
      bb = __builtin_amdgcn_mfma_f32_16x16x32_bf16(ar1, pb11, bb, 0, 0, 0);

      const int mglob = m0 + (w << 4) + col;
#pragma unroll
      for (int r = 0; r < 4; ++r) {
        int i = (quad << 2) + r;               // local l row
        int o = i + col;                       // needed p-offset (<= 30)
        int srcLane = (lane & 48) | (o & 15);
        float va = __shfl(ba[r], srcLane);
        float vb = __shfl(bb[r], srcLane);
        float bias = (o < 16) ? va : vb;
        float s = (qk[r] + bias) * kScale;

        size_t mi = ((((size_t)b << 10) + (size_t)(l0 + i)) << 10) + (size_t)mglob;
        bool msk;
        if (mkind == 0)      msk = ((const int*)mask)[mi] != 0;
        else if (mkind == 1) msk = ((const unsigned char*)mask)[mi] != 0;
        else                 msk = ((const float*)mask)[mi] != 0.f;

        float e = msk ? 0.f : __expf(s);
        unsigned short eb = f2b(e);
        sumr[r] += b2f(eb);                    // sum what we actually store
        E[i * 1032 + mglob] = (short)eb;
      }
    }
    __syncthreads();
    // ---- stage v^T tile into kvS (overwrite k tile) ----
    {
      const float4* vg = (const float4*)(v + ((size_t)b * LN + m0) * DKN);
#pragma unroll
      for (int i = 0; i < 4; ++i) {
        int j = tid + (i << 8);
        int m  = j >> 4;
        int d0 = (j & 15) << 2;
        float4 a = vg[j];
        kvS[(d0 + 0) * 72 + m] = (short)f2b(a.x);
        kvS[(d0 + 1) * 72 + m] = (short)f2b(a.y);
        kvS[(d0 + 2) * 72 + m] = (short)f2b(a.z);
        kvS[(d0 + 3) * 72 + m] = (short)f2b(a.w);
      }
    }
    __syncthreads();
    // ---- PV: acc += E_tile (A) * vT (B) ----
    {
      const int drow = (w << 4) + col;         // B-frag n = d
      bf16x8 vb0 = *(const bf16x8*)&kvS[drow * 72 + quad * 8];
      bf16x8 vb1 = *(const bf16x8*)&kvS[drow * 72 + quad * 8 + 32];
      bf16x8 ea0 = *(const bf16x8*)&E[col * 1032 + m0 + quad * 8];
      bf16x8 ea1 = *(const bf16x8*)&E[col * 1032 + m0 + quad * 8 + 32];
      acc = __builtin_amdgcn_mfma_f32_16x16x32_bf16(ea0, vb0, acc, 0, 0, 0);
      acc = __builtin_amdgcn_mfma_f32_16x16x32_bf16(ea1, vb1, acc, 0, 0, 0);
    }
  }

  // ---- row-sum reduction across 16 lanes of each quad, then across waves ----
#pragma unroll
  for (int r = 0; r < 4; ++r) {
    float vsum = sumr[r];
    vsum += __shfl_xor(vsum, 1);
    vsum += __shfl_xor(vsum, 2);
    vsum += __shfl_xor(vsum, 4);
    vsum += __shfl_xor(vsum, 8);
    if (col == 0) atomicAdd(&rowSum[(quad << 2) + r], vsum);
  }
  __syncthreads();
  if (tid < 16) invSum[tid] = 1.0f / rowSum[tid];
  __syncthreads();

  // ---- write O: out[(b*L + l0+i)*64 + 16w+col] ----
#pragma unroll
  for (int r = 0; r < 4; ++r) {
    int i = (quad << 2) + r;
    float val = acc[r] * invSum[i];
    out[(((size_t)b << 10) + (size_t)(l0 + i)) * 64 + (w << 4) + col] = val;
  }

  // ---- write attn: normalize E and stream out (16 rows x 1024 f32) ----
  float* outA = out + OUT_O_ELEMS;
#pragma unroll
  for (int it = 0; it < 16; ++it) {
    int j = tid + (it << 8);
    int row = j >> 8, c4 = j & 255;
    const ushort4 ev = *(const ushort4*)&E[row * 1032 + (c4 << 2)];
    float inv = invSum[row];
    float4 o4;
    o4.x = b2f(ev.x) * inv;
    o4.y = b2f(ev.y) * inv;
    o4.z = b2f(ev.z) * inv;
    o4.w = b2f(ev.w) * inv;
    *(float4*)&outA[((((size_t)b << 10) + (size_t)(l0 + row)) << 10) + (size_t)(c4 << 2)] = o4;
  }
}

extern "C" void kernel_launch(void* const* d_in, const int* in_sizes, int n_in,
                              void* d_out, int out_size, void* d_ws, size_t ws_size,
                              hipStream_t stream) {
  const float* q   = (const float*)d_in[0];
  const float* k   = (const float*)d_in[1];
  const float* v   = (const float*)d_in[2];
  const float* pos = (const float*)d_in[3];
  const void* mask = d_in[4];
  float* out = (float*)d_out;

  unsigned* flag = nullptr;
  if (ws_size >= 4) {
    flag = (unsigned*)d_ws;
    flag_init<<<1, 1, 0, stream>>>(flag);
    flag_scan<<<64, 256, 0, stream>>>((const unsigned*)mask, flag);
  }
  attn_kernel<<<BN * (LN / 16), 256, 0, stream>>>(q, k, v, pos, mask, flag, out);
}

// Round 2
// 748.133 us; speedup vs baseline: 1.3147x; 1.3147x over previous
//
#include <hip/hip_runtime.h>

// Problem constants
#define BN   64
#define LN   1024
#define DKN  64
#define PN   2047          // 2*L - 1
#define OUT_O_ELEMS ((size_t)BN * LN * DKN)   // 4,194,304
constexpr float kScale = 0.125f;              // 1/sqrt(64)

typedef short bf16x8 __attribute__((ext_vector_type(8)));
typedef float f32x4  __attribute__((ext_vector_type(4)));

__device__ __forceinline__ unsigned short f2b(float f) {       // round-half-up (~RNE quality)
  return (unsigned short)((__float_as_uint(f) + 0x8000u) >> 16);
}
__device__ __forceinline__ float b2f(unsigned short h) {
  return __uint_as_float(((unsigned)h) << 16);
}
__device__ __forceinline__ unsigned pk2(float x, float y) {    // two bf16 packed in a uint
  unsigned lo = (__float_as_uint(x) + 0x8000u) >> 16;
  unsigned hi = (__float_as_uint(y) + 0x8000u) & 0xFFFF0000u;
  return lo | hi;
}

union U8 { unsigned u[4]; bf16x8 v; };

__device__ __forceinline__ bf16x8 pack8(float4 a, float4 b) {
  U8 r;
  r.u[0] = pk2(a.x, a.y); r.u[1] = pk2(a.z, a.w);
  r.u[2] = pk2(b.x, b.y); r.u[3] = pk2(b.z, b.w);
  return r.v;
}

// ---------- mask dtype detection ----------
__global__ void flag_init(unsigned* f) { *f = 0u; }

__global__ void flag_scan(const unsigned* __restrict__ mw, unsigned* f) {
  int idx = blockIdx.x * 256 + threadIdx.x;
  unsigned bits = 0;
#pragma unroll
  for (int i = 0; i < 4; ++i) {
    unsigned wv = mw[idx * 4 + i];
    if (wv == 0x3F800000u) bits |= 2u;
    else if (wv > 1u)      bits |= 4u;
  }
  if (bits) atomicOr(f, bits);
}

// ---------- pre-pass: f32 -> bf16 conversions ----------
__global__ __launch_bounds__(256) void convert_f32_bf16(const float4* __restrict__ in,
                                                        uint2* __restrict__ outp) {
  int idx = blockIdx.x * 256 + threadIdx.x;
  float4 a = in[idx];
  outp[idx] = make_uint2(pk2(a.x, a.y), pk2(a.z, a.w));
}

// v [b][m][d] f32  ->  vt [b][d][m] bf16
__global__ __launch_bounds__(256) void transpose_v(const float4* __restrict__ vg,
                                                   short* __restrict__ vt) {
  __shared__ float tile[64 * 65];
  const int tid = threadIdx.x;
  const int b  = blockIdx.x >> 4;
  const int mt = blockIdx.x & 15;
  const size_t base = ((size_t)b * 1024 + mt * 64) * 16;   // float4 units
#pragma unroll
  for (int i = 0; i < 4; ++i) {
    int j = tid + (i << 8);
    float4 a = vg[base + j];
    float* d = &tile[(j >> 4) * 65 + ((j & 15) << 2)];
    d[0] = a.x; d[1] = a.y; d[2] = a.z; d[3] = a.w;
  }
  __syncthreads();
#pragma unroll
  for (int i = 0; i < 4; ++i) {
    int j  = tid + (i << 8);
    int d  = j >> 4;
    int mq = (j & 15) << 2;
    unsigned u0 = pk2(tile[(mq + 0) * 65 + d], tile[(mq + 1) * 65 + d]);
    unsigned u1 = pk2(tile[(mq + 2) * 65 + d], tile[(mq + 3) * 65 + d]);
    size_t idx = ((size_t)b * 64 + d) * 1024 + mt * 64 + mq;
    *(uint2*)(vt + idx) = make_uint2(u0, u1);
  }
}

// ---------- main fused kernel ----------
// Block: b fixed, 16 query rows. 256 threads = 4 waves.
// Phase 1 (no barriers): wave w computes S/E for m-subcolumns m0+16w+col over 16 tiles.
// Phase 2 (no barriers): wave w computes PV for d = 16w+col over 16 tiles.
__global__ __launch_bounds__(256, 4)
void attn_kernel(const float* __restrict__ qf, const float* __restrict__ kf,
                 const float* __restrict__ vf, const float* __restrict__ pf,
                 const void* __restrict__ mask, const unsigned* __restrict__ flagp,
                 const short* __restrict__ k16, const short* __restrict__ p16,
                 const short* __restrict__ vt16,
                 float* __restrict__ out) {
  __shared__ short qA[16 * 72];
  __shared__ short qrA[16 * 72];
  __shared__ short E[16 * 1032];    // unnormalized exp(s), bf16
  __shared__ float rowSum[16];
  __shared__ float invSum[16];

  const int tid  = threadIdx.x;
  const int w    = tid >> 6;
  const int lane = tid & 63;
  const int col  = lane & 15;
  const int quad = lane >> 4;

  // XCD swizzle: all 64 row-tiles of one b land on the same XCD
  int p   = blockIdx.x;
  int xcd = p & 7;
  int qq  = p >> 3;
  int rt  = qq & 63;
  int bh  = qq >> 6;
  const int b  = (bh << 3) | xcd;
  const int l0 = rt << 4;

  unsigned mflag = flagp ? flagp[0] : 0u;
  const int mkind = (mflag & 4u) ? 1 : ((mflag & 2u) ? 2 : 0);  // 0=int32 1=u8 2=f32

  if (tid < 16) rowSum[tid] = 0.0f;

  // stage qA / qrA
  {
    const float4* qg = (const float4*)qf;
    int row = tid >> 4, c4 = tid & 15;
    float4 a  = qg[((size_t)b * LN + (l0 + row)) * 16 + c4];
    float4 r_ = qg[((size_t)b * LN + (LN - 1 - l0 - row)) * 16 + c4];
    *(uint2*)&qA[row * 72 + c4 * 4]  = make_uint2(pk2(a.x, a.y), pk2(a.z, a.w));
    *(uint2*)&qrA[row * 72 + c4 * 4] = make_uint2(pk2(r_.x, r_.y), pk2(r_.z, r_.w));
  }
  __syncthreads();

  // hoisted A-fragments: A[m=lane&15][k=quad*8+j]
  const bf16x8 aq0 = *(const bf16x8*)&qA[col * 72 + quad * 8];
  const bf16x8 aq1 = *(const bf16x8*)&qA[col * 72 + quad * 8 + 32];
  const bf16x8 ar0 = *(const bf16x8*)&qrA[col * 72 + quad * 8];
  const bf16x8 ar1 = *(const bf16x8*)&qrA[col * 72 + quad * 8 + 32];

  float sumr[4] = {0.f, 0.f, 0.f, 0.f};
  const int moff = (w << 4) + col;

  // ---------------- Phase 1: scores + exp + E ----------------
  for (int t = 0; t < 16; ++t) {
    const int m0    = t << 6;
    const int mglob = m0 + moff;

    bf16x8 kb0, kb1, pb00, pb01, pb10, pb11;
    int g0 = l0 + m0 + moff;                 // <= 2031, in range
    int g1 = g0 + 16; if (g1 > PN - 1) g1 = PN - 1;   // clamped row never consumed
    if (k16) {
      const short* kr = k16 + ((size_t)b * LN + mglob) * DKN;
      kb0 = *(const bf16x8*)(kr + quad * 8);
      kb1 = *(const bf16x8*)(kr + 32 + quad * 8);
      const short* pr0 = p16 + ((size_t)b * PN + g0) * DKN;
      const short* pr1 = p16 + ((size_t)b * PN + g1) * DKN;
      pb00 = *(const bf16x8*)(pr0 + quad * 8);
      pb01 = *(const bf16x8*)(pr0 + 32 + quad * 8);
      pb10 = *(const bf16x8*)(pr1 + quad * 8);
      pb11 = *(const bf16x8*)(pr1 + 32 + quad * 8);
    } else {
      const float4* kr = (const float4*)(kf + ((size_t)b * LN + mglob) * DKN);
      kb0 = pack8(kr[quad * 2], kr[quad * 2 + 1]);
      kb1 = pack8(kr[8 + quad * 2], kr[9 + quad * 2]);
      const float4* pr0 = (const float4*)(pf + ((size_t)b * PN + g0) * DKN);
      const float4* pr1 = (const float4*)(pf + ((size_t)b * PN + g1) * DKN);
      pb00 = pack8(pr0[quad * 2], pr0[quad * 2 + 1]);
      pb01 = pack8(pr0[8 + quad * 2], pr0[9 + quad * 2]);
      pb10 = pack8(pr1[quad * 2], pr1[quad * 2 + 1]);
      pb11 = pack8(pr1[8 + quad * 2], pr1[9 + quad * 2]);
    }

    f32x4 qk = {0.f, 0.f, 0.f, 0.f};
    qk = __builtin_amdgcn_mfma_f32_16x16x32_bf16(aq0, kb0, qk, 0, 0, 0);
    qk = __builtin_amdgcn_mfma_f32_16x16x32_bf16(aq1, kb1, qk, 0, 0, 0);

    f32x4 ba = {0.f, 0.f, 0.f, 0.f}, bb = {0.f, 0.f, 0.f, 0.f};
    ba = __builtin_amdgcn_mfma_f32_16x16x32_bf16(ar0, pb00, ba, 0, 0, 0);
    ba = __builtin_amdgcn_mfma_f32_16x16x32_bf16(ar1, pb01, ba, 0, 0, 0);
    bb = __builtin_amdgcn_mfma_f32_16x16x32_bf16(ar0, pb10, bb, 0, 0, 0);
    bb = __builtin_amdgcn_mfma_f32_16x16x32_bf16(ar1, pb11, bb, 0, 0, 0);

#pragma unroll
    for (int r = 0; r < 4; ++r) {
      int i = (quad << 2) + r;               // local l row
      int o = i + col;                       // needed p-offset (<= 30)
      int srcLane = (lane & 48) | (o & 15);
      float va = __shfl(ba[r], srcLane);
      float vb = __shfl(bb[r], srcLane);
      float bias = (o < 16) ? va : vb;
      float s = (qk[r] + bias) * kScale;

      size_t mi = ((((size_t)b << 10) + (size_t)(l0 + i)) << 10) + (size_t)mglob;
      bool msk;
      if (mkind == 0)      msk = ((const int*)mask)[mi] != 0;
      else if (mkind == 1) msk = ((const unsigned char*)mask)[mi] != 0;
      else                 msk = ((const float*)mask)[mi] != 0.f;

      float e = msk ? 0.f : __expf(s);
      unsigned short eb = f2b(e);
      sumr[r] += b2f(eb);                    // sum what we actually store
      E[i * 1032 + mglob] = (short)eb;
    }
  }

  // ---- row-sum reduction ----
#pragma unroll
  for (int r = 0; r < 4; ++r) {
    float vsum = sumr[r];
    vsum += __shfl_xor(vsum, 1);
    vsum += __shfl_xor(vsum, 2);
    vsum += __shfl_xor(vsum, 4);
    vsum += __shfl_xor(vsum, 8);
    if (col == 0) atomicAdd(&rowSum[(quad << 2) + r], vsum);
  }
  __syncthreads();                            // E + rowSum visible
  if (tid < 16) invSum[tid] = 1.0f / rowSum[tid];

  // ---------------- Phase 2: PV ----------------
  f32x4 acc = {0.f, 0.f, 0.f, 0.f};           // O[l=quad*4+r][d=16w+col]
  const int drow = moff;
  for (int t = 0; t < 16; ++t) {
    const int m0 = t << 6;
    bf16x8 vb0, vb1;
    if (vt16) {
      const short* vr = vt16 + ((size_t)b * 64 + drow) * 1024 + m0;
      vb0 = *(const bf16x8*)(vr + quad * 8);
      vb1 = *(const bf16x8*)(vr + 32 + quad * 8);
    } else {
      const float* vc = vf + ((size_t)b * LN + m0) * DKN + drow;
      U8 t0, t1;
#pragma unroll
      for (int j = 0; j < 4; ++j) {
        t0.u[j] = pk2(vc[(quad * 8 + 2 * j) * 64],      vc[(quad * 8 + 2 * j + 1) * 64]);
        t1.u[j] = pk2(vc[(32 + quad * 8 + 2 * j) * 64], vc[(32 + quad * 8 + 2 * j + 1) * 64]);
      }
      vb0 = t0.v; vb1 = t1.v;
    }
    bf16x8 ea0 = *(const bf16x8*)&E[col * 1032 + m0 + quad * 8];
    bf16x8 ea1 = *(const bf16x8*)&E[col * 1032 + m0 + 32 + quad * 8];
    acc = __builtin_amdgcn_mfma_f32_16x16x32_bf16(ea0, vb0, acc, 0, 0, 0);
    acc = __builtin_amdgcn_mfma_f32_16x16x32_bf16(ea1, vb1, acc, 0, 0, 0);
  }
  __syncthreads();                            // invSum visible

  // ---- write O ----
#pragma unroll
  for (int r = 0; r < 4; ++r) {
    int i = (quad << 2) + r;
    out[(((size_t)b << 10) + (size_t)(l0 + i)) * 64 + drow] = acc[r] * invSum[i];
  }

  // ---- write attn ----
  float* outA = out + OUT_O_ELEMS;
#pragma unroll
  for (int it = 0; it < 16; ++it) {
    int j = tid + (it << 8);
    int row = j >> 8, c4 = j & 255;
    const ushort4 ev = *(const ushort4*)&E[row * 1032 + (c4 << 2)];
    float inv = invSum[row];
    float4 o4;
    o4.x = b2f(ev.x) * inv;
    o4.y = b2f(ev.y) * inv;
    o4.z = b2f(ev.z) * inv;
    o4.w = b2f(ev.w) * inv;
    *(float4*)&outA[((((size_t)b << 10) + (size_t)(l0 + row)) << 10) + (size_t)(c4 << 2)] = o4;
  }
}

extern "C" void kernel_launch(void* const* d_in, const int* in_sizes, int n_in,
                              void* d_out, int out_size, void* d_ws, size_t ws_size,
                              hipStream_t stream) {
  const float* q   = (const float*)d_in[0];
  const float* k   = (const float*)d_in[1];
  const float* v   = (const float*)d_in[2];
  const float* pos = (const float*)d_in[3];
  const void* mask = d_in[4];
  float* out = (float*)d_out;

  unsigned* flag = nullptr;
  if (ws_size >= 256) {
    flag = (unsigned*)d_ws;
    flag_init<<<1, 1, 0, stream>>>(flag);
    flag_scan<<<64, 256, 0, stream>>>((const unsigned*)mask, flag);
  }

  // bf16 pre-pass workspace layout (after 256B flag area)
  const size_t kElems  = (size_t)BN * LN * DKN;   // 4,194,304
  const size_t pElems  = (size_t)BN * PN * DKN;   // 8,384,512
  const size_t offK    = 256;
  const size_t offP    = offK + kElems * 2;       // 8,388,608
  const size_t offVT   = offP + pElems * 2;       // 16,769,024
  const size_t wsNeed  = offVT + kElems * 2;

  short *k16 = nullptr, *p16 = nullptr, *vt16 = nullptr;
  if (ws_size >= wsNeed) {
    char* base = (char*)d_ws;
    k16  = (short*)(base + offK);
    p16  = (short*)(base + offP);
    vt16 = (short*)(base + offVT);
    convert_f32_bf16<<<(int)(kElems / 1024), 256, 0, stream>>>((const float4*)k,   (uint2*)k16);
    convert_f32_bf16<<<(int)(pElems / 1024), 256, 0, stream>>>((const float4*)pos, (uint2*)p16);
    transpose_v<<<BN * 16, 256, 0, stream>>>((const float4*)v, vt16);
  }

  attn_kernel<<<BN * (LN / 16), 256, 0, stream>>>(q, k, v, pos, mask, flag,
                                                  k16, p16, vt16, out);
}